// Round 2
// baseline (558.912 us; speedup 1.0000x reference)
//
#include <hip/hip_runtime.h>
#include <hip/hip_bf16.h>

typedef __attribute__((ext_vector_type(8))) short bf16x8;
typedef __attribute__((ext_vector_type(4))) short s16x4;
typedef __attribute__((ext_vector_type(4))) float f32x4;
typedef __attribute__((ext_vector_type(4))) float float4v;

static __device__ __forceinline__ unsigned short f2b(float f) {
  unsigned int u = __builtin_bit_cast(unsigned int, f);
  u += 0x7fffu + ((u >> 16) & 1u);
  return (unsigned short)(u >> 16);
}
static __device__ __forceinline__ float b2f(unsigned short s) {
  unsigned int u = ((unsigned int)s) << 16;
  return __builtin_bit_cast(float, u);
}
static __device__ __forceinline__ float siluf(float x) {
  return x / (1.f + expf(-x));
}
// async global->LDS, 16B per lane; LDS dest = wave-uniform base + lane*16
static __device__ __forceinline__ void gl16(const unsigned short* g,
                                            unsigned short* l) {
  __builtin_amdgcn_global_load_lds(
      (const __attribute__((address_space(1))) unsigned int*)g,
      (__attribute__((address_space(3))) unsigned int*)l, 16, 0, 0);
}

// ---------------------------------------------------------------------------
// GEMM: C[M,N] = A[M,K] @ W[N,K]^T, bf16 MFMA, fp32 accum. m97 structure:
// 128 x TN block tile, BK=32, 4 waves, each wave owns 64 x (TN/2)
// (4 x TN/32 frags of 16x16x32). A/W staged via global_load_lds width=16
// (AF32: A is fp32 -> reg-stage + convert + ds_write).
// MODE 0: v += bias[n]; write fp32 of[] + bf16 ob[]                    (pre)
// MODE 1: n<512: silu(v*cw3+cb)->ob (xi); n>=512: silu(v)->ob2 (sz)     (xz)
// MODE 2: v += of[]; write back of[] + bf16 ob[]                  (out_proj)
// MODE 3: plain fp32 store to of[]                                    (xdbl)
// ---------------------------------------------------------------------------
template <int MODE, int TN, bool AF32>
__global__ __launch_bounds__(256) void gemm128(
    const void* __restrict__ Aptr, const unsigned short* __restrict__ W,
    int M, int N, int K,
    const float* __restrict__ p0, const float* __restrict__ p1,
    float* __restrict__ of, unsigned short* __restrict__ ob,
    unsigned short* __restrict__ ob2) {
  __shared__ __align__(16) unsigned short As[128 * 32];
  __shared__ __align__(16) unsigned short Ws[TN * 32];
  const int t = threadIdx.x;
  const int lane = t & 63, wave = t >> 6;
  const int bm = blockIdx.x * 128, bn = blockIdx.y * TN;
  const int wr = (wave >> 1) * 64;        // wave's row quadrant: 0 / 64
  const int wc = (wave & 1) * (TN / 2);   // wave's col quadrant
  const int lr = lane & 15, lkb = (lane >> 4) * 8;

  f32x4 acc[4][TN / 32];
#pragma unroll
  for (int i = 0; i < 4; ++i)
#pragma unroll
    for (int j = 0; j < TN / 32; ++j) acc[i][j] = (f32x4){0.f, 0.f, 0.f, 0.f};

  const unsigned short* Ab = (const unsigned short*)Aptr;
  const float* Af = (const float*)Aptr;

  // staging addresses. A tile = 128x32 bf16 = 8 chunks of 1024B; wave w
  // issues chunks 2w,2w+1. chunk c lane l: row=c*16+(l>>2), col=(l&3)*8.
  const unsigned short* a0 = nullptr;
  unsigned short* la0 = nullptr;
  const float* afs = nullptr;
  if constexpr (!AF32) {
    a0 = Ab + (long)(bm + wave * 32 + (lane >> 2)) * K + (lane & 3) * 8;
    la0 = (unsigned short*)As + wave * 1024;
  } else {
    // fp32 reg-stage: 4 iters, iter j: row=j*32+(t>>3), col=(t&7)*4
    afs = Af + (long)(bm + (t >> 3)) * K + (t & 7) * 4;
  }
  const unsigned short* w0;
  unsigned short* lw0;
  if constexpr (TN == 128) {
    w0 = W + (long)(bn + wave * 32 + (lane >> 2)) * K + (lane & 3) * 8;
    lw0 = (unsigned short*)Ws + wave * 1024;
  } else {
    w0 = W + (long)(bn + wave * 16 + (lane >> 2)) * K + (lane & 3) * 8;
    lw0 = (unsigned short*)Ws + wave * 512;
  }

  for (int k0 = 0; k0 < K; k0 += 32) {
    if constexpr (!AF32) {
      gl16(a0 + k0, la0);
      gl16(a0 + 16 * K + k0, la0 + 512);
    } else {
#pragma unroll
      for (int j = 0; j < 4; ++j) {
        float4v v = *(const float4v*)(afs + (long)j * 32 * K + k0);
        s16x4 s;
        s[0] = (short)f2b(v[0]); s[1] = (short)f2b(v[1]);
        s[2] = (short)f2b(v[2]); s[3] = (short)f2b(v[3]);
        *(s16x4*)&As[(j * 32 + (t >> 3)) * 32 + (t & 7) * 4] = s;
      }
    }
    gl16(w0 + k0, lw0);
    if constexpr (TN == 128) gl16(w0 + 16 * K + k0, lw0 + 512);
    __syncthreads();
    bf16x8 af[4], bg[TN / 32];
#pragma unroll
    for (int m = 0; m < 4; ++m)
      af[m] = *(const bf16x8*)&As[(wr + m * 16 + lr) * 32 + lkb];
#pragma unroll
    for (int n = 0; n < TN / 32; ++n)
      bg[n] = *(const bf16x8*)&Ws[(wc + n * 16 + lr) * 32 + lkb];
#pragma unroll
    for (int m = 0; m < 4; ++m)
#pragma unroll
      for (int n = 0; n < TN / 32; ++n)
        acc[m][n] =
            __builtin_amdgcn_mfma_f32_16x16x32_bf16(af[m], bg[n], acc[m][n], 0, 0, 0);
    __syncthreads();
  }

  // C/D layout (m89): col = lane&15, row = (lane>>4)*4 + reg
  const int m0 = bm + wr + (lane >> 4) * 4;
  const int n0 = bn + wc + lr;
#pragma unroll
  for (int mi = 0; mi < 4; ++mi)
#pragma unroll
    for (int ni = 0; ni < TN / 32; ++ni) {
      const int n = n0 + ni * 16;
#pragma unroll
      for (int r = 0; r < 4; ++r) {
        const int m = m0 + mi * 16 + r;
        float v = acc[mi][ni][r];
        if constexpr (MODE == 0) {
          v += p0[n];
          of[(long)m * N + n] = v;
          ob[(long)m * N + n] = f2b(v);
        } else if constexpr (MODE == 1) {
          if (n < 512) {
            float u = v * p0[n * 4 + 3] + p1[n];  // conv tap 3 + bias (L=1)
            ob[(long)m * 512 + n] = f2b(siluf(u));
          } else {
            ob2[(long)m * 512 + (n - 512)] = f2b(siluf(v));
          }
        } else if constexpr (MODE == 2) {
          float nv = of[(long)m * N + n] + v;
          of[(long)m * N + n] = nv;
          ob[(long)m * N + n] = f2b(nv);
        } else {
          of[(long)m * N + n] = v;
        }
      }
    }
}

// merged weight precast: W_pre, in_w, out_w -> bf16; x_proj -> padded 64-row bf16
__global__ __launch_bounds__(256) void precast(
    const float* __restrict__ wpre, const float* __restrict__ inw,
    const float* __restrict__ ow, const float* __restrict__ xw,
    unsigned short* __restrict__ wpreb, unsigned short* __restrict__ inwb,
    unsigned short* __restrict__ owb, unsigned short* __restrict__ xwpb) {
  const int S0 = 524288;             // 256*2048
  const int S1 = S0 + 1310720;       // + 5*1024*256
  const int S2 = S1 + 655360;        // + 5*256*512
  const int S3 = S2 + 163840;        // + 5*64*512
  int i4 = (blockIdx.x * 256 + threadIdx.x) * 4;
  if (i4 >= S3) return;
  float4v v = {0.f, 0.f, 0.f, 0.f};
  unsigned short* dst;
  if (i4 < S0) {
    v = *(const float4v*)(wpre + i4);
    dst = wpreb + i4;
  } else if (i4 < S1) {
    int o = i4 - S0;
    v = *(const float4v*)(inw + o);
    dst = inwb + o;
  } else if (i4 < S2) {
    int o = i4 - S1;
    v = *(const float4v*)(ow + o);
    dst = owb + o;
  } else {
    int o = i4 - S2;
    dst = xwpb + o;
    int k = o & 511, j = (o >> 9) & 63, b = o >> 15;
    if (j < 48) v = *(const float4v*)(xw + ((long)(b * 48 + j)) * 512 + k);
  }
  s16x4 s;
  s[0] = (short)f2b(v[0]); s[1] = (short)f2b(v[1]);
  s[2] = (short)f2b(v[2]); s[3] = (short)f2b(v[3]);
  *(s16x4*)dst = s;
}

// Per-row: dt = softplus(dtw @ xdbl[:16] + dtb); BC = dot(xdbl[16:32],xdbl[32:48])
// y = xi * (dt*BC + D) * silu(z)   (L=1 collapses the scan to this)
__global__ __launch_bounds__(256) void small_ops(
    const float* __restrict__ xdbl, const float* __restrict__ dtw,
    const float* __restrict__ dtb, const float* __restrict__ Dp,
    const unsigned short* __restrict__ xi, const unsigned short* __restrict__ sz,
    unsigned short* __restrict__ yb) {
  const int t = threadIdx.x;
  const int r0 = blockIdx.x * 32;
  for (int r = r0; r < r0 + 32; ++r) {
    const float* xr = xdbl + (long)r * 64;
    float dtr[16];
#pragma unroll
    for (int i = 0; i < 16; ++i) dtr[i] = xr[i];
    float BC = 0.f;
#pragma unroll
    for (int s = 0; s < 16; ++s) BC += xr[16 + s] * xr[32 + s];
#pragma unroll
    for (int dd = 0; dd < 2; ++dd) {
      const int d = t + dd * 256;
      float a = dtb[d];
#pragma unroll
      for (int i = 0; i < 16; ++i) a += dtw[d * 16 + i] * dtr[i];
      const float dtv = (a > 20.f) ? a : log1pf(expf(a));
      const float xiv = b2f(xi[(long)r * 512 + d]);
      const float szv = b2f(sz[(long)r * 512 + d]);
      const float y = xiv * (dtv * BC + Dp[d]) * szv;
      yb[(long)r * 512 + d] = f2b(y);
    }
  }
}

// LayerNorm(256) + classifier (8 outputs). One wave per row.
__global__ __launch_bounds__(256) void final_ln_cls(
    const float* __restrict__ h, const float* __restrict__ g,
    const float* __restrict__ be, const float* __restrict__ Wc,
    const float* __restrict__ bc, float* __restrict__ out) {
  const int wave = threadIdx.x >> 6, lane = threadIdx.x & 63;
  const int row = blockIdx.x * 4 + wave;
  const float4v* hr = (const float4v*)(h + (long)row * 256);
  float4v v = hr[lane];
  float s = v[0] + v[1] + v[2] + v[3];
#pragma unroll
  for (int o = 32; o; o >>= 1) s += __shfl_xor(s, o);
  const float mu = s * (1.f / 256.f);
  float d0 = v[0] - mu, d1 = v[1] - mu, d2 = v[2] - mu, d3 = v[3] - mu;
  float q = d0 * d0 + d1 * d1 + d2 * d2 + d3 * d3;
#pragma unroll
  for (int o = 32; o; o >>= 1) q += __shfl_xor(q, o);
  const float rs = rsqrtf(q * (1.f / 256.f) + 1e-5f);
  const float4v gv = ((const float4v*)g)[lane];
  const float4v bv = ((const float4v*)be)[lane];
  float hn[4];
  hn[0] = d0 * rs * gv[0] + bv[0];
  hn[1] = d1 * rs * gv[1] + bv[1];
  hn[2] = d2 * rs * gv[2] + bv[2];
  hn[3] = d3 * rs * gv[3] + bv[3];
  float lg[8];
#pragma unroll
  for (int o = 0; o < 8; ++o) {
    const float4v wv = ((const float4v*)(Wc + o * 256))[lane];
    float p = hn[0] * wv[0] + hn[1] * wv[1] + hn[2] * wv[2] + hn[3] * wv[3];
#pragma unroll
    for (int x = 32; x; x >>= 1) p += __shfl_xor(p, x);
    lg[o] = p;
  }
  if (lane == 0) {
#pragma unroll
    for (int o = 0; o < 8; ++o) out[(long)row * 8 + o] = lg[o] + bc[o];
  }
}

extern "C" void kernel_launch(void* const* d_in, const int* in_sizes, int n_in,
                              void* d_out, int out_size, void* d_ws,
                              size_t ws_size, hipStream_t stream) {
  const float* x      = (const float*)d_in[0];
  const float* W_pre  = (const float*)d_in[1];
  const float* b_pre  = (const float*)d_in[2];
  const float* in_w   = (const float*)d_in[3];
  const float* conv_w = (const float*)d_in[4];
  const float* conv_b = (const float*)d_in[5];
  const float* x_w    = (const float*)d_in[6];
  const float* dt_w   = (const float*)d_in[7];
  const float* dt_b   = (const float*)d_in[8];
  // d_in[9] = A_log: dead (scan starts from h0=0 and L=1)
  const float* Dp     = (const float*)d_in[10];
  const float* out_w  = (const float*)d_in[11];
  const float* ln_g   = (const float*)d_in[12];
  const float* ln_b   = (const float*)d_in[13];
  const float* W_cls  = (const float*)d_in[14];
  const float* b_cls  = (const float*)d_in[15];
  float* out = (float*)d_out;

  char* w = (char*)d_ws;
  unsigned short* wpreb = (unsigned short*)w; w += 256 * 2048 * 2;
  unsigned short* inwb  = (unsigned short*)w; w += 5 * 1024 * 256 * 2;
  unsigned short* xwpb  = (unsigned short*)w; w += 5 * 64 * 512 * 2;
  unsigned short* owb   = (unsigned short*)w; w += 5 * 256 * 512 * 2;
  float*          h     = (float*)w;          w += 8192 * 256 * 4;
  unsigned short* hb    = (unsigned short*)w; w += 8192 * 256 * 2;
  unsigned short* xib   = (unsigned short*)w; w += 8192 * 512 * 2;
  unsigned short* szb   = (unsigned short*)w; w += 8192 * 512 * 2;
  unsigned short* yb    = (unsigned short*)w; w += 8192 * 512 * 2;
  float*          xdbl  = (float*)w;          w += 8192 * 64 * 4;

  // single merged weight-precast launch
  precast<<<2592, 256, 0, stream>>>(W_pre, in_w, out_w, x_w,
                                    wpreb, inwb, owb, xwpb);

  // h = x @ W_pre^T + b_pre  (A fp32 reg-staged -> bf16; W via gload_lds)
  gemm128<0, 64, true><<<dim3(64, 4), 256, 0, stream>>>(
      (const void*)x, wpreb, 8192, 256, 2048, b_pre, nullptr, h, hb, nullptr);

  for (int blk = 0; blk < 5; ++blk) {
    // xz = h @ in_w^T ; xi = silu(xz[:512]*cw3+cb) ; sz = silu(xz[512:])
    gemm128<1, 128, false><<<dim3(64, 8), 256, 0, stream>>>(
        (const void*)hb, inwb + blk * 1024 * 256, 8192, 1024, 256,
        conv_w + blk * 512 * 4, conv_b + blk * 512, nullptr, xib, szb);
    // xdbl = xi @ x_w^T (N padded 48->64)
    gemm128<3, 64, false><<<dim3(64, 1), 256, 0, stream>>>(
        (const void*)xib, xwpb + blk * 64 * 512, 8192, 64, 512,
        nullptr, nullptr, xdbl, nullptr, nullptr);
    // dt/BC/y elementwise
    small_ops<<<256, 256, 0, stream>>>(
        xdbl, dt_w + blk * 512 * 16, dt_b + blk * 512, Dp + blk * 512,
        xib, szb, yb);
    // h += y @ out_w^T
    gemm128<2, 64, false><<<dim3(64, 4), 256, 0, stream>>>(
        (const void*)yb, owb + blk * 256 * 512, 8192, 256, 512,
        nullptr, nullptr, h, hb, nullptr);
  }

  final_ln_cls<<<2048, 256, 0, stream>>>(h, ln_g, ln_b, W_cls, b_cls, out);
}

// Round 3
// 502.251 us; speedup vs baseline: 1.1128x; 1.1128x over previous
//
#include <hip/hip_runtime.h>
#include <hip/hip_bf16.h>

typedef __attribute__((ext_vector_type(8))) short bf16x8;
typedef __attribute__((ext_vector_type(4))) short s16x4;
typedef __attribute__((ext_vector_type(4))) float f32x4;
typedef __attribute__((ext_vector_type(4))) float float4v;

static __device__ __forceinline__ unsigned short f2b(float f) {
  unsigned int u = __builtin_bit_cast(unsigned int, f);
  u += 0x7fffu + ((u >> 16) & 1u);
  return (unsigned short)(u >> 16);
}
static __device__ __forceinline__ float b2f(unsigned short s) {
  unsigned int u = ((unsigned int)s) << 16;
  return __builtin_bit_cast(float, u);
}
static __device__ __forceinline__ float siluf(float x) {
  return x / (1.f + expf(-x));
}
// async global->LDS, 16B per lane; LDS dest = wave-uniform base + lane*16
static __device__ __forceinline__ void gl16(const unsigned short* g,
                                            unsigned short* l) {
  __builtin_amdgcn_global_load_lds(
      (const __attribute__((address_space(1))) unsigned int*)g,
      (__attribute__((address_space(3))) unsigned int*)l, 16, 0, 0);
}

// ---------------------------------------------------------------------------
// Pipelined GEMM: C[M,N] = A[M,K] @ W[N,K]^T, bf16 MFMA, fp32 accum.
// TM x TN tile, BK=32, 4 waves (2x2), wave owns (TM/2)x(TN/2).
// Double-buffered LDS, 2-phase pipeline: STAGE(t+1) issued AFTER the barrier
// so the barrier's vmcnt(0) drain only catches the already-landed tile t
// (T3-minimum). AF32: A fp32 -> T14 reg-split (load post-barrier, ds_write
// next iter pre-barrier); W always via global_load_lds width=16.
// MODE 0: v += bias[n]; fp32 of[] + bf16 ob[]                          (pre)
// MODE 1: n<512: silu(v*cw3+cb)->ob (xi); else silu(v)->ob2 (sz)        (xz)
// MODE 2: v += of[]; write back of[] + bf16 ob[]                  (out_proj)
// MODE 3: plain fp32 store to of[]                                    (xdbl)
// ---------------------------------------------------------------------------
template <int MODE, int TM, int TN, bool AF32>
__global__ __launch_bounds__(256) void gemm_pl(
    const void* __restrict__ Aptr, const unsigned short* __restrict__ W,
    int M, int N, int K,
    const float* __restrict__ p0, const float* __restrict__ p1,
    float* __restrict__ of, unsigned short* __restrict__ ob,
    unsigned short* __restrict__ ob2) {
  constexpr int FM = TM / 32, FN = TN / 32;
  __shared__ __align__(16) unsigned short As[2][TM * 32];
  __shared__ __align__(16) unsigned short Ws[2][TN * 32];
  const int t = threadIdx.x, lane = t & 63, wave = t >> 6;
  const int bm = blockIdx.x * TM, bn = blockIdx.y * TN;
  const int wr = (wave >> 1) * (TM / 2), wc = (wave & 1) * (TN / 2);
  const int lr = lane & 15, lkb = (lane >> 4) * 8;

  f32x4 acc[FM][FN];
#pragma unroll
  for (int i = 0; i < FM; ++i)
#pragma unroll
    for (int j = 0; j < FN; ++j) acc[i][j] = (f32x4){0.f, 0.f, 0.f, 0.f};

  const unsigned short* Ab = (const unsigned short*)Aptr;
  const float* Af = (const float*)Aptr;

  // staging addresses (1KB chunks: lane l -> row base+(l>>2), col (l&3)*8)
  const unsigned short* ag = nullptr;
  int alo = 0;
  const float* afs = nullptr;
  if constexpr (!AF32) {
    if constexpr (TM == 128) {
      ag = Ab + (long)(bm + wave * 32 + (lane >> 2)) * K + (lane & 3) * 8;
      alo = wave * 1024;
    } else {
      ag = Ab + (long)(bm + wave * 16 + (lane >> 2)) * K + (lane & 3) * 8;
      alo = wave * 512;
    }
  } else {
    afs = Af + (long)(bm + (t >> 3)) * K + (t & 7) * 4;  // rows j*32+(t>>3)
  }
  const unsigned short* wg;
  int wlo;
  if constexpr (TN == 128) {
    wg = W + (long)(bn + wave * 32 + (lane >> 2)) * K + (lane & 3) * 8;
    wlo = wave * 1024;
  } else {
    wg = W + (long)(bn + wave * 16 + (lane >> 2)) * K + (lane & 3) * 8;
    wlo = wave * 512;
  }

  auto COMPUTE = [&](int b) {
    bf16x8 af[FM], bg[FN];
#pragma unroll
    for (int m = 0; m < FM; ++m)
      af[m] = *(const bf16x8*)&As[b][(wr + m * 16 + lr) * 32 + lkb];
#pragma unroll
    for (int n = 0; n < FN; ++n)
      bg[n] = *(const bf16x8*)&Ws[b][(wc + n * 16 + lr) * 32 + lkb];
#pragma unroll
    for (int m = 0; m < FM; ++m)
#pragma unroll
      for (int n = 0; n < FN; ++n)
        acc[m][n] = __builtin_amdgcn_mfma_f32_16x16x32_bf16(af[m], bg[n],
                                                            acc[m][n], 0, 0, 0);
  };

  const int NT = K >> 5;
  if constexpr (AF32) {
    float4v rg[TM / 32];
#pragma unroll
    for (int j = 0; j < TM / 32; ++j)
      rg[j] = *(const float4v*)(afs + (long)j * 32 * K);
    gl16(wg, &Ws[0][wlo]);
    if constexpr (TN == 128) gl16(wg + 16 * K, &Ws[0][wlo + 512]);
    for (int tt = 0; tt < NT; ++tt) {
      const int b = tt & 1;
#pragma unroll
      for (int j = 0; j < TM / 32; ++j) {
        s16x4 s;
        s[0] = (short)f2b(rg[j][0]); s[1] = (short)f2b(rg[j][1]);
        s[2] = (short)f2b(rg[j][2]); s[3] = (short)f2b(rg[j][3]);
        *(s16x4*)&As[b][(j * 32 + (t >> 3)) * 32 + (t & 7) * 4] = s;
      }
      __syncthreads();
      if (tt + 1 < NT) {
        const int k0 = (tt + 1) << 5;
#pragma unroll
        for (int j = 0; j < TM / 32; ++j)
          rg[j] = *(const float4v*)(afs + (long)j * 32 * K + k0);
        gl16(wg + k0, &Ws[b ^ 1][wlo]);
        if constexpr (TN == 128) gl16(wg + k0 + 16 * K, &Ws[b ^ 1][wlo + 512]);
      }
      COMPUTE(b);
    }
  } else {
    gl16(ag, &As[0][alo]);
    if constexpr (TM == 128) gl16(ag + 16 * K, &As[0][alo + 512]);
    gl16(wg, &Ws[0][wlo]);
    if constexpr (TN == 128) gl16(wg + 16 * K, &Ws[0][wlo + 512]);
    for (int tt = 0; tt < NT; ++tt) {
      const int b = tt & 1;
      __syncthreads();
      if (tt + 1 < NT) {
        const int k0 = (tt + 1) << 5;
        gl16(ag + k0, &As[b ^ 1][alo]);
        if constexpr (TM == 128) gl16(ag + k0 + 16 * K, &As[b ^ 1][alo + 512]);
        gl16(wg + k0, &Ws[b ^ 1][wlo]);
        if constexpr (TN == 128) gl16(wg + k0 + 16 * K, &Ws[b ^ 1][wlo + 512]);
      }
      COMPUTE(b);
    }
  }

  // C/D layout (m89): col = lane&15, row = (lane>>4)*4 + reg
  const int m0 = bm + wr + (lane >> 4) * 4;
  const int n0 = bn + wc + lr;
#pragma unroll
  for (int mi = 0; mi < FM; ++mi)
#pragma unroll
    for (int ni = 0; ni < FN; ++ni) {
      const int n = n0 + ni * 16;
#pragma unroll
      for (int r = 0; r < 4; ++r) {
        const int m = m0 + mi * 16 + r;
        float v = acc[mi][ni][r];
        if constexpr (MODE == 0) {
          v += p0[n];
          of[(long)m * N + n] = v;
          ob[(long)m * N + n] = f2b(v);
        } else if constexpr (MODE == 1) {
          if (n < 512) {
            float u = v * p0[n * 4 + 3] + p1[n];  // conv tap 3 + bias (L=1)
            ob[(long)m * 512 + n] = f2b(siluf(u));
          } else {
            ob2[(long)m * 512 + (n - 512)] = f2b(siluf(v));
          }
        } else if constexpr (MODE == 2) {
          float nv = of[(long)m * N + n] + v;
          of[(long)m * N + n] = nv;
          ob[(long)m * N + n] = f2b(nv);
        } else {
          of[(long)m * N + n] = v;
        }
      }
    }
}

// merged weight precast: W_pre, in_w, out_w -> bf16; x_proj -> padded 64-row bf16
__global__ __launch_bounds__(256) void precast(
    const float* __restrict__ wpre, const float* __restrict__ inw,
    const float* __restrict__ ow, const float* __restrict__ xw,
    unsigned short* __restrict__ wpreb, unsigned short* __restrict__ inwb,
    unsigned short* __restrict__ owb, unsigned short* __restrict__ xwpb) {
  const int S0 = 524288;             // 256*2048
  const int S1 = S0 + 1310720;       // + 5*1024*256
  const int S2 = S1 + 655360;        // + 5*256*512
  const int S3 = S2 + 163840;        // + 5*64*512
  int i4 = (blockIdx.x * 256 + threadIdx.x) * 4;
  if (i4 >= S3) return;
  float4v v = {0.f, 0.f, 0.f, 0.f};
  unsigned short* dst;
  if (i4 < S0) {
    v = *(const float4v*)(wpre + i4);
    dst = wpreb + i4;
  } else if (i4 < S1) {
    int o = i4 - S0;
    v = *(const float4v*)(inw + o);
    dst = inwb + o;
  } else if (i4 < S2) {
    int o = i4 - S1;
    v = *(const float4v*)(ow + o);
    dst = owb + o;
  } else {
    int o = i4 - S2;
    dst = xwpb + o;
    int k = o & 511, j = (o >> 9) & 63, b = o >> 15;
    if (j < 48) v = *(const float4v*)(xw + ((long)(b * 48 + j)) * 512 + k);
  }
  s16x4 s;
  s[0] = (short)f2b(v[0]); s[1] = (short)f2b(v[1]);
  s[2] = (short)f2b(v[2]); s[3] = (short)f2b(v[3]);
  *(s16x4*)dst = s;
}

// Per-row: dt = softplus(dtw @ xdbl[:16] + dtb); BC = dot(xdbl[16:32],xdbl[32:48])
// y = xi * (dt*BC + D) * silu(z)   (L=1 collapses the scan to this)
__global__ __launch_bounds__(256) void small_ops(
    const float* __restrict__ xdbl, const float* __restrict__ dtw,
    const float* __restrict__ dtb, const float* __restrict__ Dp,
    const unsigned short* __restrict__ xi, const unsigned short* __restrict__ sz,
    unsigned short* __restrict__ yb) {
  const int t = threadIdx.x;
  const int r0 = blockIdx.x * 32;
  float wreg[2][16];
  float bias[2], Dv[2];
#pragma unroll
  for (int dd = 0; dd < 2; ++dd) {
    const int d = t + dd * 256;
    bias[dd] = dtb[d];
    Dv[dd] = Dp[d];
#pragma unroll
    for (int i = 0; i < 16; ++i) wreg[dd][i] = dtw[d * 16 + i];
  }
  for (int r = r0; r < r0 + 32; ++r) {
    const float* xr = xdbl + (long)r * 64;
    float dtr[16];
#pragma unroll
    for (int i = 0; i < 16; ++i) dtr[i] = xr[i];
    float BC = 0.f;
#pragma unroll
    for (int s = 0; s < 16; ++s) BC += xr[16 + s] * xr[32 + s];
#pragma unroll
    for (int dd = 0; dd < 2; ++dd) {
      const int d = t + dd * 256;
      float a = bias[dd];
#pragma unroll
      for (int i = 0; i < 16; ++i) a += wreg[dd][i] * dtr[i];
      const float dtv = (a > 20.f) ? a : log1pf(expf(a));
      const float xiv = b2f(xi[(long)r * 512 + d]);
      const float szv = b2f(sz[(long)r * 512 + d]);
      const float y = xiv * (dtv * BC + Dv[dd]) * szv;
      yb[(long)r * 512 + d] = f2b(y);
    }
  }
}

// LayerNorm(256) + classifier (8 outputs). One wave per row.
__global__ __launch_bounds__(256) void final_ln_cls(
    const float* __restrict__ h, const float* __restrict__ g,
    const float* __restrict__ be, const float* __restrict__ Wc,
    const float* __restrict__ bc, float* __restrict__ out) {
  const int wave = threadIdx.x >> 6, lane = threadIdx.x & 63;
  const int row = blockIdx.x * 4 + wave;
  const float4v* hr = (const float4v*)(h + (long)row * 256);
  float4v v = hr[lane];
  float s = v[0] + v[1] + v[2] + v[3];
#pragma unroll
  for (int o = 32; o; o >>= 1) s += __shfl_xor(s, o);
  const float mu = s * (1.f / 256.f);
  float d0 = v[0] - mu, d1 = v[1] - mu, d2 = v[2] - mu, d3 = v[3] - mu;
  float q = d0 * d0 + d1 * d1 + d2 * d2 + d3 * d3;
#pragma unroll
  for (int o = 32; o; o >>= 1) q += __shfl_xor(q, o);
  const float rs = rsqrtf(q * (1.f / 256.f) + 1e-5f);
  const float4v gv = ((const float4v*)g)[lane];
  const float4v bv = ((const float4v*)be)[lane];
  float hn[4];
  hn[0] = d0 * rs * gv[0] + bv[0];
  hn[1] = d1 * rs * gv[1] + bv[1];
  hn[2] = d2 * rs * gv[2] + bv[2];
  hn[3] = d3 * rs * gv[3] + bv[3];
  float lg[8];
#pragma unroll
  for (int o = 0; o < 8; ++o) {
    const float4v wv = ((const float4v*)(Wc + o * 256))[lane];
    float p = hn[0] * wv[0] + hn[1] * wv[1] + hn[2] * wv[2] + hn[3] * wv[3];
#pragma unroll
    for (int x = 32; x; x >>= 1) p += __shfl_xor(p, x);
    lg[o] = p;
  }
  if (lane == 0) {
#pragma unroll
    for (int o = 0; o < 8; ++o) out[(long)row * 8 + o] = lg[o] + bc[o];
  }
}

extern "C" void kernel_launch(void* const* d_in, const int* in_sizes, int n_in,
                              void* d_out, int out_size, void* d_ws,
                              size_t ws_size, hipStream_t stream) {
  const float* x      = (const float*)d_in[0];
  const float* W_pre  = (const float*)d_in[1];
  const float* b_pre  = (const float*)d_in[2];
  const float* in_w   = (const float*)d_in[3];
  const float* conv_w = (const float*)d_in[4];
  const float* conv_b = (const float*)d_in[5];
  const float* x_w    = (const float*)d_in[6];
  const float* dt_w   = (const float*)d_in[7];
  const float* dt_b   = (const float*)d_in[8];
  // d_in[9] = A_log: dead (scan starts from h0=0 and L=1)
  const float* Dp     = (const float*)d_in[10];
  const float* out_w  = (const float*)d_in[11];
  const float* ln_g   = (const float*)d_in[12];
  const float* ln_b   = (const float*)d_in[13];
  const float* W_cls  = (const float*)d_in[14];
  const float* b_cls  = (const float*)d_in[15];
  float* out = (float*)d_out;

  char* w = (char*)d_ws;
  unsigned short* wpreb = (unsigned short*)w; w += 256 * 2048 * 2;
  unsigned short* inwb  = (unsigned short*)w; w += 5 * 1024 * 256 * 2;
  unsigned short* xwpb  = (unsigned short*)w; w += 5 * 64 * 512 * 2;
  unsigned short* owb   = (unsigned short*)w; w += 5 * 256 * 512 * 2;
  float*          h     = (float*)w;          w += 8192 * 256 * 4;
  unsigned short* hb    = (unsigned short*)w; w += 8192 * 256 * 2;
  unsigned short* xib   = (unsigned short*)w; w += 8192 * 512 * 2;
  unsigned short* szb   = (unsigned short*)w; w += 8192 * 512 * 2;
  unsigned short* yb    = (unsigned short*)w; w += 8192 * 512 * 2;
  float*          xdbl  = (float*)w;          w += 8192 * 64 * 4;

  // single merged weight-precast launch
  precast<<<2592, 256, 0, stream>>>(W_pre, in_w, out_w, x_w,
                                    wpreb, inwb, owb, xwpb);

  // h = x @ W_pre^T + b_pre  (A fp32 reg-split staged; W via gload_lds)
  gemm_pl<0, 64, 64, true><<<dim3(128, 4), 256, 0, stream>>>(
      (const void*)x, wpreb, 8192, 256, 2048, b_pre, nullptr, h, hb, nullptr);

  for (int blk = 0; blk < 5; ++blk) {
    // xz = h @ in_w^T ; xi = silu(xz[:512]*cw3+cb) ; sz = silu(xz[512:])
    gemm_pl<1, 128, 128, false><<<dim3(64, 8), 256, 0, stream>>>(
        (const void*)hb, inwb + blk * 1024 * 256, 8192, 1024, 256,
        conv_w + blk * 512 * 4, conv_b + blk * 512, nullptr, xib, szb);
    // xdbl = xi @ x_w^T (N padded 48->64)
    gemm_pl<3, 64, 64, false><<<dim3(128, 1), 256, 0, stream>>>(
        (const void*)xib, xwpb + blk * 64 * 512, 8192, 64, 512,
        nullptr, nullptr, xdbl, nullptr, nullptr);
    // dt/BC/y elementwise
    small_ops<<<256, 256, 0, stream>>>(
        xdbl, dt_w + blk * 512 * 16, dt_b + blk * 512, Dp + blk * 512,
        xib, szb, yb);
    // h += y @ out_w^T
    gemm_pl<2, 64, 64, false><<<dim3(128, 4), 256, 0, stream>>>(
        (const void*)yb, owb + blk * 256 * 512, 8192, 256, 512,
        nullptr, nullptr, h, hb, nullptr);
  }

  final_ln_cls<<<2048, 256, 0, stream>>>(h, ln_g, ln_b, W_cls, b_cls, out);
}

// Round 4
// 420.332 us; speedup vs baseline: 1.3297x; 1.1949x over previous
//
#include <hip/hip_runtime.h>
#include <hip/hip_bf16.h>

typedef __attribute__((ext_vector_type(8))) short bf16x8;
typedef __attribute__((ext_vector_type(4))) short s16x4;
typedef __attribute__((ext_vector_type(4))) float f32x4;
typedef __attribute__((ext_vector_type(4))) float float4v;

static __device__ __forceinline__ unsigned short f2b(float f) {
  unsigned int u = __builtin_bit_cast(unsigned int, f);
  u += 0x7fffu + ((u >> 16) & 1u);
  return (unsigned short)(u >> 16);
}
static __device__ __forceinline__ float b2f(unsigned short s) {
  unsigned int u = ((unsigned int)s) << 16;
  return __builtin_bit_cast(float, u);
}
static __device__ __forceinline__ float siluf(float x) {
  return x / (1.f + expf(-x));
}
// async global->LDS, 16B/lane; LDS dest = wave-uniform base + lane*16
static __device__ __forceinline__ void gl16(const void* g, void* l) {
  __builtin_amdgcn_global_load_lds(
      (const __attribute__((address_space(1))) unsigned int*)g,
      (__attribute__((address_space(3))) unsigned int*)l, 16, 0, 0);
}
template <int N>
static __device__ __forceinline__ void waitv() {
  if constexpr (N == 0) asm volatile("s_waitcnt vmcnt(0)" ::: "memory");
  else if constexpr (N == 2) asm volatile("s_waitcnt vmcnt(2)" ::: "memory");
  else if constexpr (N == 3) asm volatile("s_waitcnt vmcnt(3)" ::: "memory");
  else if constexpr (N == 4) asm volatile("s_waitcnt vmcnt(4)" ::: "memory");
  else if constexpr (N == 6) asm volatile("s_waitcnt vmcnt(6)" ::: "memory");
  else if constexpr (N == 8) asm volatile("s_waitcnt vmcnt(8)" ::: "memory");
}

// ---------------------------------------------------------------------------
// Deep-pipelined GEMM: C[M,N] = A[M,K] @ W[N,K]^T, bf16 MFMA, fp32 accum.
// TM x TN tile, BK=32, 4 waves (2x2). DEPTH-4 LDS ring, stage tile t+2 at
// loop top, counted s_waitcnt vmcnt(2*LPT) + raw s_barrier (ONE per iter,
// never vmcnt(0) mid-loop) -- T3/T4. LDS chunk XOR-swizzle applied on BOTH
// sides (pre-swizzled global source for global_load_lds + swizzled ds_read,
// rule #21). 1-D grid with bijective XCD swizzle, bn-fastest (T1).
// AF32: A fp32 staged raw into LDS, converted to bf16 after ds_read.
// MODE 0: v += bias[n]; fp32 of[] + bf16 ob[]                          (pre)
// MODE 1: n<512: silu(v*cw3+cb)->ob (xi); else silu(v)->ob2 (sz)        (xz)
// MODE 2: v += of[]; write back of[] + bf16 ob[]                  (out_proj)
// MODE 3: plain fp32 store to of[]                                    (xdbl)
// ---------------------------------------------------------------------------
template <int MODE, int TM, int TN, bool AF32>
__global__ __launch_bounds__(256) void gemm_pl(
    const void* __restrict__ Aptr, const unsigned short* __restrict__ W,
    int N, int K, int GY,
    const float* __restrict__ p0, const float* __restrict__ p1,
    float* __restrict__ of, unsigned short* __restrict__ ob,
    unsigned short* __restrict__ ob2) {
  constexpr int FM = TM / 32, FN = TN / 32;
  constexpr int IA = AF32 ? TM / 32 : TM / 64;  // A gl16 instrs per wave
  constexpr int IW = TN / 64;                   // W gl16 instrs per wave
  constexpr int LPT = IA + IW;                  // loads per wave per tile
  constexpr int ABYT = AF32 ? 4 : 2;
  __shared__ __align__(16) char AsRaw[4 * TM * 32 * ABYT];
  __shared__ __align__(16) unsigned short Ws[4][TN * 32];

  const int t = threadIdx.x, lane = t & 63, wave = t >> 6;
  const int lr = lane & 15;
  // bijective XCD swizzle (all grids divisible by 8), bn-fastest for A reuse
  const int q = gridDim.x >> 3;
  const int s = (blockIdx.x & 7) * q + (blockIdx.x >> 3);
  const int bm = (s / GY) * TM, bn = (s % GY) * TN;
  const int wr = (wave >> 1) * (TM / 2), wc = (wave & 1) * (TN / 2);

  f32x4 acc[FM][FN];
#pragma unroll
  for (int i = 0; i < FM; ++i)
#pragma unroll
    for (int j = 0; j < FN; ++j) acc[i][j] = (f32x4){0.f, 0.f, 0.f, 0.f};

  // --- staging source pointers (global pre-swizzled to match LDS layout) ---
  const unsigned short* Ab = (const unsigned short*)Aptr;
  const float* Af = (const float*)Aptr;
  const unsigned short* agB = nullptr;
  const float* agF = nullptr;
  if constexpr (AF32) {
    // f32 chunk = 4 floats; layout pos p holds logical chunk p ^ (row&7)
    agF = Af + (long)(bm + wave * (TM / 4) + (lane >> 3)) * K +
          ((lane & 7) ^ ((lane >> 3) & 7)) * 4;
  } else {
    // bf16 chunk = 8 shorts; layout pos p holds logical chunk p ^ ((row>>1)&3)
    agB = Ab + (long)(bm + wave * (TM / 4) + (lane >> 2)) * K +
          ((lane & 3) ^ ((lane >> 3) & 3)) * 8;
  }
  const unsigned short* wgB =
      W + (long)(bn + wave * (TN / 4) + (lane >> 2)) * K +
      ((lane & 3) ^ ((lane >> 3) & 3)) * 8;

  auto STAGE = [&](int k0, int b) {  // k0 in elements
    if constexpr (AF32) {
      float* lb = (float*)AsRaw + b * TM * 32;
#pragma unroll
      for (int j = 0; j < IA; ++j)
        gl16(agF + k0 + (long)j * 8 * K, lb + (wave * (TM / 4) + j * 8) * 32);
    } else {
      unsigned short* lb = (unsigned short*)AsRaw + b * TM * 32;
#pragma unroll
      for (int j = 0; j < IA; ++j)
        gl16(agB + k0 + (long)j * 16 * K, lb + (wave * (TM / 4) + j * 16) * 32);
    }
#pragma unroll
    for (int j = 0; j < IW; ++j)
      gl16(wgB + k0 + (long)j * 16 * K, &Ws[b][(wave * (TN / 4) + j * 16) * 32]);
  };

  auto COMPUTE = [&](int b) {
    bf16x8 af[FM], bg[FN];
    const int sw = ((lane >> 4) ^ ((lane >> 1) & 3)) * 8;  // swizzled read off
    if constexpr (AF32) {
      const float* As = (const float*)AsRaw + b * TM * 32;
      const int s8 = lane & 7, g2 = (lane >> 4) * 2;
#pragma unroll
      for (int m = 0; m < FM; ++m) {
        const float* pr = As + (wr + m * 16 + lr) * 32;
        f32x4 lo = *(const f32x4*)&pr[(g2 ^ s8) * 4];
        f32x4 hi = *(const f32x4*)&pr[((g2 + 1) ^ s8) * 4];
        bf16x8 v;
        v[0] = (short)f2b(lo[0]); v[1] = (short)f2b(lo[1]);
        v[2] = (short)f2b(lo[2]); v[3] = (short)f2b(lo[3]);
        v[4] = (short)f2b(hi[0]); v[5] = (short)f2b(hi[1]);
        v[6] = (short)f2b(hi[2]); v[7] = (short)f2b(hi[3]);
        af[m] = v;
      }
    } else {
      const unsigned short* As = (const unsigned short*)AsRaw + b * TM * 32;
#pragma unroll
      for (int m = 0; m < FM; ++m)
        af[m] = *(const bf16x8*)&As[(wr + m * 16 + lr) * 32 + sw];
    }
#pragma unroll
    for (int n = 0; n < FN; ++n)
      bg[n] = *(const bf16x8*)&Ws[b][(wc + n * 16 + lr) * 32 + sw];
#pragma unroll
    for (int m = 0; m < FM; ++m)
#pragma unroll
      for (int n = 0; n < FN; ++n)
        acc[m][n] = __builtin_amdgcn_mfma_f32_16x16x32_bf16(af[m], bg[n],
                                                            acc[m][n], 0, 0, 0);
  };

  const int NT = K >> 5;  // always >= 8 here
  STAGE(0, 0);
  STAGE(32, 1);
  for (int tt = 0; tt < NT; ++tt) {
    if (tt + 2 < NT) {
      STAGE((tt + 2) << 5, (tt + 2) & 3);
      waitv<2 * LPT>();
    } else if (tt + 1 < NT) {
      waitv<LPT>();
    } else {
      waitv<0>();
    }
    __builtin_amdgcn_s_barrier();
    COMPUTE(tt & 3);
    __builtin_amdgcn_sched_barrier(0);
  }

  // C/D layout (m89): col = lane&15, row = (lane>>4)*4 + reg
  const int m0 = bm + wr + (lane >> 4) * 4;
  const int n0 = bn + wc + lr;
#pragma unroll
  for (int mi = 0; mi < FM; ++mi)
#pragma unroll
    for (int ni = 0; ni < FN; ++ni) {
      const int n = n0 + ni * 16;
#pragma unroll
      for (int r = 0; r < 4; ++r) {
        const int m = m0 + mi * 16 + r;
        float v = acc[mi][ni][r];
        if constexpr (MODE == 0) {
          v += p0[n];
          of[(long)m * N + n] = v;
          ob[(long)m * N + n] = f2b(v);
        } else if constexpr (MODE == 1) {
          if (n < 512) {
            float u = v * p0[n * 4 + 3] + p1[n];  // conv tap 3 + bias (L=1)
            ob[(long)m * 512 + n] = f2b(siluf(u));
          } else {
            ob2[(long)m * 512 + (n - 512)] = f2b(siluf(v));
          }
        } else if constexpr (MODE == 2) {
          float nv = of[(long)m * N + n] + v;
          of[(long)m * N + n] = nv;
          ob[(long)m * N + n] = f2b(nv);
        } else {
          of[(long)m * N + n] = v;
        }
      }
    }
}

// merged weight precast: W_pre, in_w, out_w -> bf16; x_proj -> padded 64-row bf16
__global__ __launch_bounds__(256) void precast(
    const float* __restrict__ wpre, const float* __restrict__ inw,
    const float* __restrict__ ow, const float* __restrict__ xw,
    unsigned short* __restrict__ wpreb, unsigned short* __restrict__ inwb,
    unsigned short* __restrict__ owb, unsigned short* __restrict__ xwpb) {
  const int S0 = 524288;        // 256*2048
  const int S1 = S0 + 1310720;  // + 5*1024*256
  const int S2 = S1 + 655360;   // + 5*256*512
  const int S3 = S2 + 163840;   // + 5*64*512
  int i4 = (blockIdx.x * 256 + threadIdx.x) * 4;
  if (i4 >= S3) return;
  float4v v = {0.f, 0.f, 0.f, 0.f};
  unsigned short* dst;
  if (i4 < S0) {
    v = *(const float4v*)(wpre + i4);
    dst = wpreb + i4;
  } else if (i4 < S1) {
    int o = i4 - S0;
    v = *(const float4v*)(inw + o);
    dst = inwb + o;
  } else if (i4 < S2) {
    int o = i4 - S1;
    v = *(const float4v*)(ow + o);
    dst = owb + o;
  } else {
    int o = i4 - S2;
    dst = xwpb + o;
    int k = o & 511, j = (o >> 9) & 63, b = o >> 15;
    if (j < 48) v = *(const float4v*)(xw + ((long)(b * 48 + j)) * 512 + k);
  }
  s16x4 sv;
  sv[0] = (short)f2b(v[0]); sv[1] = (short)f2b(v[1]);
  sv[2] = (short)f2b(v[2]); sv[3] = (short)f2b(v[3]);
  *(s16x4*)dst = sv;
}

// Per-row: dt = softplus(dtw @ xdbl[:16] + dtb); BC = dot(xdbl[16:32],xdbl[32:48])
// y = xi * (dt*BC + D) * silu(z)   (L=1 collapses the scan to this)
// thread t: 4 consecutive d = (t&127)*4; row group g = t>>7 (rows r0+g, step 2)
__global__ __launch_bounds__(256) void small_ops(
    const float* __restrict__ xdbl, const float* __restrict__ dtw,
    const float* __restrict__ dtb, const float* __restrict__ Dp,
    const unsigned short* __restrict__ xi, const unsigned short* __restrict__ sz,
    unsigned short* __restrict__ yb) {
  const int t = threadIdx.x;
  const int dq = (t & 127) * 4;
  const int g = t >> 7;
  float wreg[4][16], bias[4], Dv[4];
#pragma unroll
  for (int j = 0; j < 4; ++j) {
    bias[j] = dtb[dq + j];
    Dv[j] = Dp[dq + j];
#pragma unroll
    for (int i = 0; i < 16; ++i) wreg[j][i] = dtw[(dq + j) * 16 + i];
  }
  const int r0 = blockIdx.x * 32 + g;
  for (int rr = 0; rr < 16; ++rr) {
    const int r = r0 + rr * 2;
    const float* xr = xdbl + (long)r * 64;
    float dtr[16];
#pragma unroll
    for (int i = 0; i < 16; ++i) dtr[i] = xr[i];
    float BC = 0.f;
#pragma unroll
    for (int ss = 0; ss < 16; ++ss) BC += xr[16 + ss] * xr[32 + ss];
    s16x4 xv = *(const s16x4*)&xi[(long)r * 512 + dq];
    s16x4 zv = *(const s16x4*)&sz[(long)r * 512 + dq];
    s16x4 yo;
#pragma unroll
    for (int j = 0; j < 4; ++j) {
      float a = bias[j];
#pragma unroll
      for (int i = 0; i < 16; ++i) a += wreg[j][i] * dtr[i];
      const float dtv = (a > 20.f) ? a : log1pf(expf(a));
      const float y = b2f((unsigned short)xv[j]) * (dtv * BC + Dv[j]) *
                      b2f((unsigned short)zv[j]);
      yo[j] = (short)f2b(y);
    }
    *(s16x4*)&yb[(long)r * 512 + dq] = yo;
  }
}

// LayerNorm(256) + classifier (8 outputs). One wave per row.
__global__ __launch_bounds__(256) void final_ln_cls(
    const float* __restrict__ h, const float* __restrict__ g,
    const float* __restrict__ be, const float* __restrict__ Wc,
    const float* __restrict__ bc, float* __restrict__ out) {
  const int wave = threadIdx.x >> 6, lane = threadIdx.x & 63;
  const int row = blockIdx.x * 4 + wave;
  const float4v* hr = (const float4v*)(h + (long)row * 256);
  float4v v = hr[lane];
  float s = v[0] + v[1] + v[2] + v[3];
#pragma unroll
  for (int o = 32; o; o >>= 1) s += __shfl_xor(s, o);
  const float mu = s * (1.f / 256.f);
  float d0 = v[0] - mu, d1 = v[1] - mu, d2 = v[2] - mu, d3 = v[3] - mu;
  float qq = d0 * d0 + d1 * d1 + d2 * d2 + d3 * d3;
#pragma unroll
  for (int o = 32; o; o >>= 1) qq += __shfl_xor(qq, o);
  const float rs = rsqrtf(qq * (1.f / 256.f) + 1e-5f);
  const float4v gv = ((const float4v*)g)[lane];
  const float4v bv = ((const float4v*)be)[lane];
  float hn[4];
  hn[0] = d0 * rs * gv[0] + bv[0];
  hn[1] = d1 * rs * gv[1] + bv[1];
  hn[2] = d2 * rs * gv[2] + bv[2];
  hn[3] = d3 * rs * gv[3] + bv[3];
  float lg[8];
#pragma unroll
  for (int o = 0; o < 8; ++o) {
    const float4v wv = ((const float4v*)(Wc + o * 256))[lane];
    float p = hn[0] * wv[0] + hn[1] * wv[1] + hn[2] * wv[2] + hn[3] * wv[3];
#pragma unroll
    for (int x = 32; x; x >>= 1) p += __shfl_xor(p, x);
    lg[o] = p;
  }
  if (lane == 0) {
#pragma unroll
    for (int o = 0; o < 8; ++o) out[(long)row * 8 + o] = lg[o] + bc[o];
  }
}

extern "C" void kernel_launch(void* const* d_in, const int* in_sizes, int n_in,
                              void* d_out, int out_size, void* d_ws,
                              size_t ws_size, hipStream_t stream) {
  const float* x      = (const float*)d_in[0];
  const float* W_pre  = (const float*)d_in[1];
  const float* b_pre  = (const float*)d_in[2];
  const float* in_w   = (const float*)d_in[3];
  const float* conv_w = (const float*)d_in[4];
  const float* conv_b = (const float*)d_in[5];
  const float* x_w    = (const float*)d_in[6];
  const float* dt_w   = (const float*)d_in[7];
  const float* dt_b   = (const float*)d_in[8];
  // d_in[9] = A_log: dead (scan starts from h0=0 and L=1)
  const float* Dp     = (const float*)d_in[10];
  const float* out_w  = (const float*)d_in[11];
  const float* ln_g   = (const float*)d_in[12];
  const float* ln_b   = (const float*)d_in[13];
  const float* W_cls  = (const float*)d_in[14];
  const float* b_cls  = (const float*)d_in[15];
  float* out = (float*)d_out;

  char* w = (char*)d_ws;
  unsigned short* wpreb = (unsigned short*)w; w += 256 * 2048 * 2;
  unsigned short* inwb  = (unsigned short*)w; w += 5 * 1024 * 256 * 2;
  unsigned short* xwpb  = (unsigned short*)w; w += 5 * 64 * 512 * 2;
  unsigned short* owb   = (unsigned short*)w; w += 5 * 256 * 512 * 2;
  float*          h     = (float*)w;          w += 8192 * 256 * 4;
  unsigned short* hb    = (unsigned short*)w; w += 8192 * 256 * 2;
  unsigned short* xib   = (unsigned short*)w; w += 8192 * 512 * 2;
  unsigned short* szb   = (unsigned short*)w; w += 8192 * 512 * 2;
  unsigned short* yb    = (unsigned short*)w; w += 8192 * 512 * 2;
  float*          xdbl  = (float*)w;          w += 8192 * 64 * 4;

  precast<<<2592, 256, 0, stream>>>(W_pre, in_w, out_w, x_w,
                                    wpreb, inwb, owb, xwpb);

  // h = x @ W_pre^T + b_pre  (fp32 A staged raw, converted post-ds_read)
  gemm_pl<0, 64, 64, true><<<512, 256, 0, stream>>>(
      (const void*)x, wpreb, 256, 2048, 4, b_pre, nullptr, h, hb, nullptr);

  for (int blk = 0; blk < 5; ++blk) {
    // xz = h @ in_w^T ; xi = silu(xz[:512]*cw3+cb) ; sz = silu(xz[512:])
    gemm_pl<1, 128, 128, false><<<512, 256, 0, stream>>>(
        (const void*)hb, inwb + blk * 1024 * 256, 1024, 256, 8,
        conv_w + blk * 512 * 4, conv_b + blk * 512, nullptr, xib, szb);
    // xdbl = xi @ x_w^T (N padded 48->64)
    gemm_pl<3, 64, 64, false><<<128, 256, 0, stream>>>(
        (const void*)xib, xwpb + blk * 64 * 512, 64, 512, 1,
        nullptr, nullptr, xdbl, nullptr, nullptr);
    // dt/BC/y elementwise
    small_ops<<<256, 256, 0, stream>>>(
        xdbl, dt_w + blk * 512 * 16, dt_b + blk * 512, Dp + blk * 512,
        xib, szb, yb);
    // h += y @ out_w^T
    gemm_pl<2, 64, 64, false><<<512, 256, 0, stream>>>(
        (const void*)yb, owb + blk * 256 * 512, 256, 512, 4,
        nullptr, nullptr, h, hb, nullptr);
  }

  final_ln_cls<<<2048, 256, 0, stream>>>(h, ln_g, ln_b, W_cls, b_cls, out);
}